// Round 2
// baseline (587.452 us; speedup 1.0000x reference)
//
#include <hip/hip_runtime.h>
#include <hip/hip_bf16.h>
#include <stdint.h>

typedef unsigned short u16;
typedef __attribute__((ext_vector_type(8))) short short8;   // 8 bf16 = 4 VGPRs
typedef __attribute__((ext_vector_type(4))) float floatx4;

__device__ __forceinline__ u16 f2bf(float f) {
    union { unsigned int i; float f; } v; v.f = f;
    unsigned int r = v.i + 0x7fff + ((v.i >> 16) & 1);  // RNE
    return (u16)(r >> 16);
}

// B=8, CIN=512, COUT=256, H=W=64, K=3, SDIM=512.  All I/O fp32.
// ws layout (bytes):
#define OFF_S    0           // s[b][ci]        8*512 f32
#define OFF_DEM  16384       // scale*demod     8*256 f32
#define OFF_W2   32768       // sum_kk w^2      256*512 f32
#define OFF_BM   1048576     // BmatT[n][k]     1024*4608 bf16 (k-contig per n)
#define OFF_XMT  16777216    // xm NHWC padded  [8][66][66][512] bf16

// ---- s[b,ci] = style . mod_weight[ci] * (1/sqrt(512)) + mod_bias[ci]   (fp32 exact)
__global__ void k_style(const float* __restrict__ style, const float* __restrict__ mw,
                        const float* __restrict__ mb, float* __restrict__ S) {
    int t = blockIdx.x * 256 + threadIdx.x;          // 4096
    int b = t >> 9, ci = t & 511;
    const float* sr = style + b * 512;
    const float* wr = mw + ci * 512;
    float acc = 0.f;
    for (int d = 0; d < 512; d += 4) {
        float4 sv = *(const float4*)(sr + d);
        float4 wv = *(const float4*)(wr + d);
        acc += sv.x * wv.x + sv.y * wv.y + sv.z * wv.z + sv.w * wv.w;
    }
    S[t] = acc * 0.044194173824159216f + mb[ci];
}

// ---- w2[co,ci] = sum over 3x3 of weight^2
__global__ void k_w2(const float* __restrict__ w, float* __restrict__ W2) {
    int t = blockIdx.x * 256 + threadIdx.x;          // 131072
    const float* p = w + t * 9;
    float a = 0.f;
    #pragma unroll
    for (int i = 0; i < 9; ++i) { float v = p[i]; a += v * v; }
    W2[t] = a;
}

// ---- D[b,co] = scale * rsqrt(scale^2 * sum_ci w2*s^2 + 1e-8)
__global__ void k_demod(const float* __restrict__ W2, const float* __restrict__ S,
                        float* __restrict__ D) {
    int t = blockIdx.x * 256 + threadIdx.x;          // 2048
    int b = t >> 8, co = t & 255;
    const float* wr = W2 + co * 512;
    const float* sr = S + b * 512;
    float a = 0.f;
    for (int ci = 0; ci < 512; ++ci) { float s = sr[ci]; a += wr[ci] * s * s; }
    D[t] = 0.014731391274719738f * rsqrtf(a * (1.0f / 4608.0f) + 1e-8f);
}

// ---- composite (convT stride2 + blur) parity kernels:
// BmatT[n = py*512 + co*2 + px][k = (dy*3+dx)*512 + ci]
//   = (1/16) * sum_{a,b} w[co,ci,a,b] * KT[py][dy][a] * KT[px][dx][b]
__global__ void k_bmat(const float* __restrict__ Wt, u16* __restrict__ Bm) {
    int t = blockIdx.x * 256 + threadIdx.x;          // 524288 = 4*256*512
    int ci = t & 511;
    int rest = t >> 9;
    int co = rest & 255;
    int p = rest >> 8;                               // 0..3
    int py = p >> 1, px = p & 1;
    const float KT[2][3][3] = {
        {{0.f,1.f,3.f},{3.f,3.f,1.f},{1.f,0.f,0.f}},   // even output rows
        {{0.f,0.f,1.f},{1.f,3.f,3.f},{3.f,1.f,0.f}}    // odd output rows
    };
    float wv[3][3];
    const float* wp = Wt + (co * 512 + ci) * 9;
    #pragma unroll
    for (int a = 0; a < 3; ++a)
        #pragma unroll
        for (int bq = 0; bq < 3; ++bq) wv[a][bq] = wp[a * 3 + bq];
    int n = py * 512 + co * 2 + px;
    size_t base = (size_t)n * 4608 + ci;
    #pragma unroll
    for (int dyi = 0; dyi < 3; ++dyi) {
        #pragma unroll
        for (int dxi = 0; dxi < 3; ++dxi) {
            float val = 0.f;
            #pragma unroll
            for (int a = 0; a < 3; ++a) {
                float ky = KT[py][dyi][a];
                #pragma unroll
                for (int bq = 0; bq < 3; ++bq)
                    val += wv[a][bq] * (ky * KT[px][dxi][bq]);
            }
            Bm[base + (dyi * 3 + dxi) * 512] = f2bf(val * 0.0625f);
        }
    }
}

// ---- zero xmt (incl. 1px zero border)
__global__ void k_zero(u16* __restrict__ XMT) {
    size_t t = (size_t)blockIdx.x * 256 + threadIdx.x;   // 8712 blocks: 2,230,272 * 8 elems
    *(short8*)(XMT + t * 8) = (short8)0;
}

// ---- xmt[b][y][x][ci] = x[b][ci][y-1][x-1] * s[b][ci]  (fp32 NCHW -> bf16 padded NHWC)
__global__ void k_fill(const float* __restrict__ X, const float* __restrict__ S,
                       u16* __restrict__ XMT) {
    __shared__ __align__(16) u16 tile[64][80];           // [w][ci], 160B stride
    int blk = blockIdx.x;                                // 8 b * 64 h * 8 ci-groups
    int ci0g = (blk & 7) * 64;
    int h = (blk >> 3) & 63;
    int b = blk >> 9;
    int t = threadIdx.x;
    #pragma unroll
    for (int it = 0; it < 4; ++it) {
        int idx = it * 256 + t;                          // 0..1023 : 64 ci * 16 chunks of 4
        int ci_l = idx >> 4, ch = idx & 15;
        float4 v = *(const float4*)(X + (((b * 512 + ci0g + ci_l) * 64 + h) * 64 + ch * 4));
        float s = S[b * 512 + ci0g + ci_l];
        tile[ch * 4 + 0][ci_l] = f2bf(v.x * s);
        tile[ch * 4 + 1][ci_l] = f2bf(v.y * s);
        tile[ch * 4 + 2][ci_l] = f2bf(v.z * s);
        tile[ch * 4 + 3][ci_l] = f2bf(v.w * s);
    }
    __syncthreads();
    #pragma unroll
    for (int it = 0; it < 2; ++it) {
        int idx = it * 256 + t;                          // 64 w * 8 chunks of 8
        int wl = idx >> 3, c8 = idx & 7;
        short8 v = *(const short8*)(&tile[wl][c8 * 8]);
        *(short8*)(XMT + (((size_t)(b * 66 + h + 1) * 66 + (wl + 1)) * 512 + ci0g + c8 * 8)) = v;
    }
}

// ---- main implicit GEMM: M=32768 (b,r,c) x N=1024 (py,co,px) x K=4608 (dy,dx,ci)
// out[b,co,2r+py,2c+px] = D[b,co] * sum_k xm[b,r+dy-1,c+dx-1,ci] * BmatT[n][k]
__global__ __launch_bounds__(256, 2)
void k_main(const u16* __restrict__ X, const u16* __restrict__ Bm,
            const float* __restrict__ D, float* __restrict__ out) {
    __shared__ __align__(16) char smem[34048];   // staging 32KB / epilogue-half 33792B
    const int t = threadIdx.x;
    const int bid = blockIdx.x;                  // 2048 = 256 bm * 8 bn (bn fastest)
    const int bn = bid & 7, bm = bid >> 3;
    const int w = t >> 6, L = t & 63;
    const int wm = w >> 1, wn = w & 1;
    const int quad = L >> 4, col = L & 15;

    // staging: slot sigma = ii*256+t holds 16B chunk; phys chunk (sigma&7) of row
    // ml=sigma>>3 holds logical k-seg ks=(sigma&7)^(ml&7)  (XOR swizzle)
    int preA[4], preB[4];
    #pragma unroll
    for (int ii = 0; ii < 4; ++ii) {
        int sig = ii * 256 + t;
        int ml = sig >> 3;
        int ks = (sig & 7) ^ (ml & 7);
        int mg = bm * 128 + ml;
        int b = mg >> 12, r = (mg >> 6) & 63, c = mg & 63;
        preA[ii] = ((b * 66 + r) * 66 + c) * 512 + ks * 8;
        int ng = bn * 128 + ml;
        preB[ii] = ng * 4608 + ks * 8;
    }

    floatx4 acc[4][4];
    #pragma unroll
    for (int mt = 0; mt < 4; ++mt)
        #pragma unroll
        for (int nt = 0; nt < 4; ++nt) acc[mt][nt] = (floatx4){0.f, 0.f, 0.f, 0.f};

    for (int kt = 0; kt < 72; ++kt) {
        int j = kt >> 3;
        int dy = j / 3, dx = j - dy * 3;
        int offA = (dy * 66 + dx) * 512 + (kt & 7) * 64;
        int offB = kt * 64;
        #pragma unroll
        for (int ii = 0; ii < 4; ++ii) {
            __builtin_amdgcn_global_load_lds(
                (const __attribute__((address_space(1))) void*)(X + preA[ii] + offA),
                (__attribute__((address_space(3))) void*)(smem + (ii * 256 + w * 64) * 16),
                16, 0, 0);
            __builtin_amdgcn_global_load_lds(
                (const __attribute__((address_space(1))) void*)(Bm + preB[ii] + offB),
                (__attribute__((address_space(3))) void*)(smem + 16384 + (ii * 256 + w * 64) * 16),
                16, 0, 0);
        }
        __syncthreads();
        #pragma unroll
        for (int kk = 0; kk < 2; ++kk) {
            short8 af[4], bfr[4];
            #pragma unroll
            for (int mt = 0; mt < 4; ++mt) {
                int m = wm * 64 + mt * 16 + col;
                af[mt] = *(const short8*)(smem + m * 128 + (((kk * 4 + quad) ^ (m & 7)) * 16));
            }
            #pragma unroll
            for (int nt = 0; nt < 4; ++nt) {
                int n = wn * 64 + nt * 16 + col;
                bfr[nt] = *(const short8*)(smem + 16384 + n * 128 + (((kk * 4 + quad) ^ (n & 7)) * 16));
            }
            #pragma unroll
            for (int mt = 0; mt < 4; ++mt)
                #pragma unroll
                for (int nt = 0; nt < 4; ++nt)
                    acc[mt][nt] = __builtin_amdgcn_mfma_f32_16x16x32_bf16(
                        af[mt], bfr[nt], acc[mt][nt], 0, 0, 0);
        }
        __syncthreads();
    }

    // epilogue: scale by D, transpose via LDS in two 32-cout halves, fp32 float4 stores
    const int b  = bm >> 5;
    const int r0 = (bm * 2) & 63;                 // block covers image rows r0, r0+1
    const int py = bn >> 2;
    const int co0 = (bn & 3) * 64;                // block covers 64 couts, both px
    float* ep = (float*)smem;                     // [co_r 32][rl 2][x 128], stride 264 f32
    #pragma unroll
    for (int half = 0; half < 2; ++half) {
        #pragma unroll
        for (int nt = 0; nt < 4; ++nt) {
            int nl = wn * 64 + nt * 16 + col;
            int co_l = nl >> 1, px = nl & 1;
            if ((co_l >> 5) == half) {
                float ds = D[b * 256 + co0 + co_l];
                int co_r = co_l & 31;
                #pragma unroll
                for (int mt = 0; mt < 4; ++mt) {
                    #pragma unroll
                    for (int reg = 0; reg < 4; ++reg) {
                        int c = mt * 16 + quad * 4 + reg;   // D: row=quad*4+reg (M), col (N)
                        ep[co_r * 264 + wm * 128 + 2 * c + px] = acc[mt][nt][reg] * ds;
                    }
                }
            }
        }
        __syncthreads();
        #pragma unroll
        for (int it = 0; it < 8; ++it) {
            int slot = it * 256 + t;               // 64 (co_r,rl) * 32 chunks of 4 f32
            int gr = slot >> 5;
            int co_r = gr >> 1, rl = gr & 1;
            int x0 = (slot & 31) * 4;
            float4 v = *(const float4*)(ep + co_r * 264 + rl * 128 + x0);
            int y = 2 * (r0 + rl) + py;
            size_t o = ((size_t)((b * 256 + co0 + half * 32 + co_r) * 128 + y)) * 128 + x0;
            *(float4*)(out + o) = v;
        }
        __syncthreads();
    }
}

extern "C" void kernel_launch(void* const* d_in, const int* in_sizes, int n_in,
                              void* d_out, int out_size, void* d_ws, size_t ws_size,
                              hipStream_t stream) {
    const float* x      = (const float*)d_in[0];   // [8,512,64,64] f32
    const float* style  = (const float*)d_in[1];   // [8,512]
    const float* weight = (const float*)d_in[2];   // [1,256,512,3,3]
    const float* mw     = (const float*)d_in[3];   // [512,512]
    const float* mb     = (const float*)d_in[4];   // [512]
    float* out = (float*)d_out;                    // [8,256,128,128] f32
    char* ws = (char*)d_ws;
    float* S   = (float*)(ws + OFF_S);
    float* DEM = (float*)(ws + OFF_DEM);
    float* W2  = (float*)(ws + OFF_W2);
    u16*  BM   = (u16*)(ws + OFF_BM);
    u16*  XMT  = (u16*)(ws + OFF_XMT);

    k_style<<<16,   256, 0, stream>>>(style, mw, mb, S);
    k_w2   <<<512,  256, 0, stream>>>(weight, W2);
    k_demod<<<8,    256, 0, stream>>>(W2, S, DEM);
    k_bmat <<<2048, 256, 0, stream>>>(weight, BM);
    k_zero <<<8712, 256, 0, stream>>>(XMT);
    k_fill <<<4096, 256, 0, stream>>>(x, S, XMT);
    k_main <<<2048, 256, 0, stream>>>(XMT, BM, DEM, out);
}